// Round 8
// baseline (358.263 us; speedup 1.0000x reference)
//
#include <hip/hip_runtime.h>
#include <cstddef>
#include <cstdint>

// MinGRU: g/v/d = x@W{g,v,d}^T + b; xs = sigmoid(g)*tanh(v); a = 0.001+0.998*sigmoid(d)
// h_t = a_t*h_{t-1} + xs_t (causal scan over S). Output h [B,S,D] f32.
// B=4, S=4096, D=1024.
// R12: R11 A/B proved counted-vmcnt ~= syncthreads at 1 block/CU lockstep (no
//      other-phase waves to overlap with). Restore cross-block overlap at the
//      256x192 tile: LDS 112KB -> 56KB via BK 64->32 (intensity unchanged;
//      staging still 27us total vs MFMA 41us) + 4x 64-row epilogue quarter-
//      passes (R8's proven pattern) -> 2 blocks/CU, 4 waves/SIMD. Staging is
//      wave-role-split (waves 0-3: A, 4 chunks; waves 4-7: B, 3 chunks) with
//      per-role counted vmcnt. No scheduling hints (m141/m190 lesson).
// Pipeline: cvt -> gemm_fused (w/ segment fold) -> scan3 (carry rebuild + out).

typedef _Float16 f16;
typedef f16 f16x8 __attribute__((ext_vector_type(8)));
typedef float f32x4 __attribute__((ext_vector_type(4)));

#define S_LEN 4096
#define D_DIM 1024
#define B_DIM 4
#define M_TOT (B_DIM * S_LEN)  // 16384
#define N_TOT (3 * D_DIM)      // 3072
#define K_TOT D_DIM            // 1024

#define CLEN 16
#define CPB (S_LEN / CLEN)   // 256 chunks per batch
#define NCHUNK (B_DIM * CPB) // 1024 total chunks

#define SEG 16               // chunks per scan segment
#define NSEG (CPB / SEG)     // 16 segments per batch

// ---------------- merged f32 -> f16 convert: x, then interleaved weights ----------------
__device__ __forceinline__ void cvt8(const float* s, f16* d) {
  f32x4 a = *(const f32x4*)s;
  f32x4 b = *(const f32x4*)(s + 4);
  f16x8 o;
  o[0] = (f16)a[0]; o[1] = (f16)a[1]; o[2] = (f16)a[2]; o[3] = (f16)a[3];
  o[4] = (f16)b[0]; o[5] = (f16)b[1]; o[6] = (f16)b[2]; o[7] = (f16)b[3];
  *(f16x8*)d = o;
}

__global__ void cvt_all_kernel(const float* __restrict__ x, const float* __restrict__ w0,
                               const float* __restrict__ w1, const float* __restrict__ w2,
                               f16* __restrict__ Ah, f16* __restrict__ Bh) {
  int i = (blockIdx.x * 256 + threadIdx.x) * 8;
  if (i < M_TOT * K_TOT) {
    cvt8(x + i, Ah + i);
  } else {
    int w = i - M_TOT * K_TOT;   // 0 .. 3*2^20
    int row = w >> 10;           // interleaved dst row 0..3071
    int col = w & 1023;
    int srow = row / 3;
    int mat = row - srow * 3;
    const float* s = (mat == 0) ? w0 : (mat == 1) ? w1 : w2;
    cvt8(s + srow * 1024 + col, Bh + w);
  }
}

// ---------------- fused GEMM + activation + chunk/segment scan ----------------
#define BM 256
#define BN 192
#define BK 32
#define RAWP 200  // raw g/v/d tile pitch (halves), 64-row quarter-pass
#define XSP 72    // xs/a tile pitch (halves), padded vs bank conflicts

// LDS (halves): A buf0 [0,8192) buf1 [8192,16384)       (256 rows x 32)
//               B buf0 [16384,22528) buf1 [22528,28672) (192 rows x 32)
// epilogue overlay (per 64-row quarter): Raw [0,12800) = 64x200,
//   xsL [12800,17408) = 64x72, aLs [17408,22016) = 64x72,
//   segP/segH f32 @ halves [22016,26112).
#define AS_OFF 0
#define BS_OFF 16384
#define ABUF 8192
#define BBUF 6144
#define SMEM_H 28672  // 57344 B -> 2 blocks/CU

__device__ __forceinline__ void gl_lds16(const void* g, void* l) {
  __builtin_amdgcn_global_load_lds((const __attribute__((address_space(1))) void*)g,
                                   (__attribute__((address_space(3))) void*)l, 16, 0, 0);
}

__device__ __forceinline__ void act(float g, float v, float d, f16& xh, f16& ah) {
  float sg = 1.f / (1.f + __expf(-g));
  float tv = 1.f - 2.f / (__expf(2.f * v) + 1.f);
  float sd = 1.f / (1.f + __expf(-d));
  xh = (f16)(sg * tv);
  ah = (f16)(0.001f + 0.998f * sd);
}

// grid = 1024 blocks (XCD-swizzled to 16 N x 64 M), 512 threads = 8 waves.
__global__ __launch_bounds__(512, 4) void gemm_fused_kernel(
    const f16* __restrict__ A, const f16* __restrict__ Bt,
    const float* __restrict__ bg, const float* __restrict__ bv,
    const float* __restrict__ bd,
    f16* __restrict__ xsA, f16* __restrict__ aA,
    float* __restrict__ P, float* __restrict__ H,
    float* __restrict__ SP, float* __restrict__ SH) {
  __shared__ __attribute__((aligned(16))) f16 smem[SMEM_H];
  const int tid = threadIdx.x;
  const int lane = tid & 63;
  const int wave = tid >> 6;

  // bijective XCD swizzle (nwg=1024 % 8 == 0): XCD c owns 128 consecutive
  // orig ids = 8 M-panels x 16 N-blocks, N-major -> A panel stays L2-hot.
  const int wg = blockIdx.x;
  const int orig = (wg & 7) * 128 + (wg >> 3);
  const int bx = orig & 15;   // N block 0..15
  const int by = orig >> 4;   // M block 0..63
  const int m0 = by * BM;
  const int bn0 = bx * BN;    // interleaved B row base (multiple of 3)

  // bias loads issued before the K-loop; they're the oldest vmcnt entries and
  // drain with the first counted wait (vmcnt counts NEWEST-N remaining).
  const int d = tid & 63;        // channel within block (64 channels)
  const int gd = (bx << 6) + d;  // global channel
  const float Bg = bg[gd], Bv = bv[gd], Bd_ = bd[gd];

  // ---- staging: wave-role-split. waves 0-3 stage A (4 chunks of 64 rows),
  // waves 4-7 stage B (3 chunks). Per 256-thread group: 64 rows x 4 slots of
  // 8 halves. LDS dest linear (gl_lds rule); global SOURCE slot pre-swizzled:
  // LDS[row][p] = global[row][p ^ ((row>>1)&3)] (involution, rule #21).
  const int tau = tid & 255;
  const int srow = tau >> 2;                         // 0..63
  const int sslot = (tau & 3) ^ ((tau >> 3) & 3);    // = p ^ ((srow>>1)&3)
  const f16* aSrc = A + (size_t)(m0 + srow) * K_TOT + sslot * 8;
  const f16* bSrc = Bt + (size_t)(bn0 + srow) * K_TOT + sslot * 8;
  f16* aDst0 = smem + AS_OFF + tau * 8;              // + buf*ABUF + r*2048
  f16* bDst0 = smem + BS_OFF + tau * 8;              // + buf*BBUF + r*2048

  // ---- fragment addressing ----
  const int wm = (wave >> 1) * 64;  // 0/64/128/192
  const int wn = (wave & 1) * 96;   // 0/96
  const int lm = lane & 15;
  // read-side swizzle: logical slot q=lane>>4 sits at q ^ ((row>>1)&3);
  // (row>>1)&3 == (lm>>1)&3 (wm, i*16, j*16 are all 0 mod 8).
  const int kswz = (((lane >> 4) ^ ((lm >> 1) & 3)) << 3);

  f32x4 acc[4][6] = {};

  // stage(tile, buf): A-waves 4 gl_lds16, B-waves 3.
  auto STAGE = [&](int tile, int buf) {
    const size_t k0 = (size_t)tile * BK;
    if (wave < 4) {
#pragma unroll
      for (int r = 0; r < 4; ++r)
        gl_lds16(aSrc + (size_t)r * 64 * K_TOT + k0, aDst0 + buf * ABUF + r * 2048);
    } else {
#pragma unroll
      for (int r = 0; r < 3; ++r)
        gl_lds16(bSrc + (size_t)r * 64 * K_TOT + k0, bDst0 + buf * BBUF + r * 2048);
    }
  };

  // ---- prologue: both buffers in flight ----
  STAGE(0, 0);
  STAGE(1, 1);

  // ---- main loop: 32 K-tiles, counted vmcnt (role-specific), raw barriers,
  // no scheduling hints. iter t: [vmcnt(N): tile t landed, t+1 flying]
  // [barrier] [10 ds_read + 24 MFMA on buf t&1] [barrier] [stage t+2].
  for (int t = 0; t < 32; ++t) {
    if (t < 31) {
      if (wave < 4) asm volatile("s_waitcnt vmcnt(4)" ::: "memory");
      else          asm volatile("s_waitcnt vmcnt(3)" ::: "memory");
    } else {
      asm volatile("s_waitcnt vmcnt(0)" ::: "memory");
    }
    __builtin_amdgcn_s_barrier();

    const f16* Acur = smem + AS_OFF + (t & 1) * ABUF;
    const f16* Bcur = smem + BS_OFF + (t & 1) * BBUF;
    f16x8 af[4], bf[6];
#pragma unroll
    for (int i = 0; i < 4; ++i)
      af[i] = *(const f16x8*)&Acur[(wm + i * 16 + lm) * BK + kswz];
#pragma unroll
    for (int j = 0; j < 6; ++j)
      bf[j] = *(const f16x8*)&Bcur[(wn + j * 16 + lm) * BK + kswz];
#pragma unroll
    for (int i = 0; i < 4; ++i)
#pragma unroll
      for (int j = 0; j < 6; ++j)
        acc[i][j] = __builtin_amdgcn_mfma_f32_16x16x32_f16(af[i], bf[j], acc[i][j], 0, 0, 0);

    if (t < 30) {
      __builtin_amdgcn_s_barrier();  // all waves consumed buf t&1
      STAGE(t + 2, t & 1);
    }
  }
  __syncthreads();  // full drain before epilogue overlays the staging LDS

  // ---- epilogue: four 64-row quarter-passes through LDS overlay ----
  f16* Raw = smem;
  f16* xsL = smem + 12800;
  f16* aLs = smem + 17408;
  float* segP = (float*)(smem + 22016);  // [16][64] chunk p per (chunk, channel)
  float* segH = segP + 1024;             // [16][64] chunk h
  const int cc = (tid >> 6) & 3;         // chunk within quarter (tid<256 active)

#pragma unroll
  for (int qq = 0; qq < 4; ++qq) {
    // 1) wave-pair qq dumps its acc rows (64 rows x 192 cols) into Raw
    if ((wave >> 1) == qq) {
      const int r0 = (lane >> 4) << 2;   // local row in quarter
      const int c0 = wn + lm;            // channel-triple column
#pragma unroll
      for (int i = 0; i < 4; ++i)
#pragma unroll
        for (int j = 0; j < 6; ++j)
#pragma unroll
          for (int r = 0; r < 4; ++r)
            Raw[(r0 + i * 16 + r) * RAWP + c0 + j * 16] = (f16)acc[i][j][r];
    }
    __syncthreads();

    // 2) activation + chunk-local scan; thread = (chunk cc, channel d)
    if (tid < 256) {
      float p = 1.f, h = 0.f;
#pragma unroll
      for (int i = 0; i < CLEN; ++i) {
        const int r = cc * CLEN + i;
        const f16* t3 = &Raw[r * RAWP + 3 * d];
        f16 xh, ah;
        act((float)t3[0] + Bg, (float)t3[1] + Bv, (float)t3[2] + Bd_, xh, ah);
        xsL[r * XSP + d] = xh;
        aLs[r * XSP + d] = ah;
        // use ROUNDED values so scan3 recomposition is exactly consistent
        float xf = (float)xh, af_ = (float)ah;
        h = af_ * h + xf;
        p *= af_;
      }
      const int gs = (m0 >> 4) + qq * 4 + cc;  // global chunk index = m/16
      P[(size_t)gs * D_DIM + gd] = p;
      H[(size_t)gs * D_DIM + gd] = h;
      segP[(qq * 4 + cc) * 64 + d] = p;
      segH[(qq * 4 + cc) * 64 + d] = h;
    }
    __syncthreads();

    // 3) coalesced xs/a global stores (64 rows x 64 cols)
    {
      const int row = tid >> 3;
      const int col = (tid & 7) * 8;
      const size_t gi = (size_t)(m0 + qq * 64 + row) * D_DIM + (bx << 6) + col;
      *(f16x8*)(xsA + gi) = *(const f16x8*)&xsL[row * XSP + col];
      *(f16x8*)(aA + gi) = *(const f16x8*)&aLs[row * XSP + col];
    }
    __syncthreads();  // next quarter overwrites Raw/xsL/aLs
  }

  // ---- segment aggregate: block's 256 rows = segment `by` (same fold order
  // as the original scan2a -> bitwise-identical SP/SH).
  if (tid < 64) {
    float ps = 1.f, hs = 0.f;
#pragma unroll
    for (int s = 0; s < 16; ++s) {
      const float pp = segP[s * 64 + tid];
      const float hh = segH[s * 64 + tid];
      hs = pp * hs + hh;
      ps *= pp;
    }
    const size_t so = (size_t)by * D_DIM + (bx << 6) + tid;
    SP[so] = ps;
    SH[so] = hs;
  }
}

// ---------------- scan pass 3: rebuild carry from SP/SH + P/H, rescan, out ----------------
// ck (thus segment s, chain lengths) is block-uniform -> non-divergent chains.
// Arithmetic order matches the original scan2bc -> identical carry values.
__global__ void scan3_kernel(const f16* __restrict__ xsA, const f16* __restrict__ aA,
                             const float* __restrict__ P, const float* __restrict__ Hc,
                             const float* __restrict__ SP, const float* __restrict__ SH,
                             float* __restrict__ out) {
  const int u = blockIdx.x * 256 + threadIdx.x;
  const int cg = u & 127;
  const int b = (u >> 7) & 3;
  const int ck = u >> 9;   // 0..255, uniform per block
  const int s = ck >> 4;   // segment index, uniform per block
  const int ch = cg * 8;

  float h[8];
#pragma unroll
  for (int j = 0; j < 8; ++j) h[j] = 0.f;

  // carry chain over preceding segment aggregates (<=15 steps, L2-resident)
  for (int s2 = 0; s2 < s; ++s2) {
    const size_t off = (size_t)(b * NSEG + s2) * D_DIM + ch;
    f32x4 sp0 = *(const f32x4*)(SP + off);
    f32x4 sp1 = *(const f32x4*)(SP + off + 4);
    f32x4 sh0 = *(const f32x4*)(SH + off);
    f32x4 sh1 = *(const f32x4*)(SH + off + 4);
#pragma unroll
    for (int j = 0; j < 4; ++j) h[j] = sp0[j] * h[j] + sh0[j];
#pragma unroll
    for (int j = 0; j < 4; ++j) h[4 + j] = sp1[j] * h[4 + j] + sh1[j];
  }
  // carry chain over preceding chunks within this segment (<=15 steps)
  for (int c = s * SEG; c < ck; ++c) {
    const size_t off = (size_t)(b * CPB + c) * D_DIM + ch;
    f32x4 p0 = *(const f32x4*)(P + off);
    f32x4 p1 = *(const f32x4*)(P + off + 4);
    f32x4 h0 = *(const f32x4*)(Hc + off);
    f32x4 h1 = *(const f32x4*)(Hc + off + 4);
#pragma unroll
    for (int j = 0; j < 4; ++j) h[j] = p0[j] * h[j] + h0[j];
#pragma unroll
    for (int j = 0; j < 4; ++j) h[4 + j] = p1[j] * h[4 + j] + h1[j];
  }

  // rescan the 16 timesteps of this chunk, write f32 output
  const int t0 = ck * CLEN;
#pragma unroll 4
  for (int t = t0; t < t0 + CLEN; ++t) {
    const size_t m = (size_t)b * S_LEN + t;
    f16x8 xs8 = *(const f16x8*)(xsA + m * D_DIM + ch);
    f16x8 a8 = *(const f16x8*)(aA + m * D_DIM + ch);
#pragma unroll
    for (int j = 0; j < 8; ++j) h[j] = (float)a8[j] * h[j] + (float)xs8[j];
    float* op = out + m * D_DIM + ch;
    *(f32x4*)op = *(f32x4*)h;
    *(f32x4*)(op + 4) = *(f32x4*)(h + 4);
  }
}

extern "C" void kernel_launch(void* const* d_in, const int* in_sizes, int n_in,
                              void* d_out, int out_size, void* d_ws, size_t ws_size,
                              hipStream_t stream) {
  const float* x = (const float*)d_in[0];
  const float* Wg = (const float*)d_in[1];
  const float* bg = (const float*)d_in[2];
  const float* Wv = (const float*)d_in[3];
  const float* bv = (const float*)d_in[4];
  const float* Wd = (const float*)d_in[5];
  const float* bd = (const float*)d_in[6];
  float* out = (float*)d_out;

  // workspace layout (~110.5 MiB). No carry buffer (scan3 rebuilds carries).
  char* ws = (char*)d_ws;
  f16* Ah = (f16*)(ws);                     // 33,554,432 B
  f16* Bh = (f16*)(ws + 33554432);          // 6,291,456 B (interleaved weights)
  f16* xsA = (f16*)(ws + 39845888);         // 33,554,432 B
  f16* aA = (f16*)(ws + 73400320);          // 33,554,432 B
  float* P = (float*)(ws + 106954752);      // NCHUNK*1024*4 = 4,194,304 B
  float* H = (float*)(ws + 111149056);      // 4,194,304 B
  float* SP = (float*)(ws + 115343360);     // 262,144 B
  float* SH = (float*)(ws + 115605504);     // 262,144 B  (end 115,867,648)

  cvt_all_kernel<<<9728, 256, 0, stream>>>(x, Wg, Wv, Wd, Ah, Bh);
  gemm_fused_kernel<<<1024, 512, 0, stream>>>(Ah, Bh, bg, bv, bd, xsA, aA, P, H, SP, SH);
  scan3_kernel<<<512, 256, 0, stream>>>(xsA, aA, P, H, SP, SH, out);
}

// Round 11
// 310.677 us; speedup vs baseline: 1.1532x; 1.1532x over previous
//
#include <hip/hip_runtime.h>
#include <cstddef>
#include <cstdint>

// MinGRU: g/v/d = x@W{g,v,d}^T + b; xs = sigmoid(g)*tanh(v); a = 0.001+0.998*sigmoid(d)
// h_t = a_t*h_{t-1} + xs_t (causal scan over S). Output h [B,S,D] f32.
// B=4, S=4096, D=1024.
// R13 (3rd submit; prior two runs died on container acquisition — no compile/
//      correctness signal; ledger re-audited, both structural parents R11/R12
//      are harness-verified):
//      R12's regression = register cliff (launch_bounds(512,4) -> 128 regs/wave
//      vs ~165 needed -> acc spilled to scratch: WRITE_SIZE 74->248 MB). The
//      2-blocks/CU path is closed for a 64x96 wave tile. Instead: deepen the
//      pipeline at 1 block/CU. Triple-buffered BK=32 (LDS 86KB): stage(t+3)
//      issued at end of tile t -> 2 compute iterations (~500+cy) of slack vs
//      R11's 1 (~250cy), so the top-of-tile vmcnt wait leaves the critical
//      path (m218 mechanism: pipeline depth, not hints). Role-split staging
//      (waves 0-3 A / 4-7 B, per-role counted vmcnt), launch_bounds(512,2)
//      (256 regs/wave, no spill), setprio around the MFMA cluster only.
// Pipeline: cvt -> gemm_fused (w/ segment fold) -> scan3 (carry rebuild + out).

typedef _Float16 f16;
typedef f16 f16x8 __attribute__((ext_vector_type(8)));
typedef float f32x4 __attribute__((ext_vector_type(4)));

#define S_LEN 4096
#define D_DIM 1024
#define B_DIM 4
#define M_TOT (B_DIM * S_LEN)  // 16384
#define N_TOT (3 * D_DIM)      // 3072
#define K_TOT D_DIM            // 1024

#define CLEN 16
#define CPB (S_LEN / CLEN)   // 256 chunks per batch
#define NCHUNK (B_DIM * CPB) // 1024 total chunks

#define SEG 16               // chunks per scan segment
#define NSEG (CPB / SEG)     // 16 segments per batch

// ---------------- merged f32 -> f16 convert: x, then interleaved weights ----------------
__device__ __forceinline__ void cvt8(const float* s, f16* d) {
  f32x4 a = *(const f32x4*)s;
  f32x4 b = *(const f32x4*)(s + 4);
  f16x8 o;
  o[0] = (f16)a[0]; o[1] = (f16)a[1]; o[2] = (f16)a[2]; o[3] = (f16)a[3];
  o[4] = (f16)b[0]; o[5] = (f16)b[1]; o[6] = (f16)b[2]; o[7] = (f16)b[3];
  *(f16x8*)d = o;
}

__global__ void cvt_all_kernel(const float* __restrict__ x, const float* __restrict__ w0,
                               const float* __restrict__ w1, const float* __restrict__ w2,
                               f16* __restrict__ Ah, f16* __restrict__ Bh) {
  int i = (blockIdx.x * 256 + threadIdx.x) * 8;
  if (i < M_TOT * K_TOT) {
    cvt8(x + i, Ah + i);
  } else {
    int w = i - M_TOT * K_TOT;   // 0 .. 3*2^20
    int row = w >> 10;           // interleaved dst row 0..3071
    int col = w & 1023;
    int srow = row / 3;
    int mat = row - srow * 3;
    const float* s = (mat == 0) ? w0 : (mat == 1) ? w1 : w2;
    cvt8(s + srow * 1024 + col, Bh + w);
  }
}

// ---------------- fused GEMM + activation + chunk/segment scan ----------------
#define BM 256
#define BN 192
#define BK 32
#define RAWP 200  // raw g/v/d tile pitch (halves), 64-row quarter-pass
#define XSP 72    // xs/a tile pitch (halves), padded vs bank conflicts

// LDS (halves), TRIPLE buffered:
//   A bufs at 0, 8192, 16384          (256 rows x 32 each)
//   B bufs at 24576, 30720, 36864     (192 rows x 32 each)   end 43008
// epilogue overlay (per 64-row quarter): Raw [0,12800) = 64x200,
//   xsL [12800,17408), aLs [17408,22016), segP/segH f32 [22016,26112).
#define AS_OFF 0
#define BS_OFF 24576
#define ABUF 8192
#define BBUF 6144
#define SMEM_H 43008  // 86016 B -> 1 block/CU

__device__ __forceinline__ void gl_lds16(const void* g, void* l) {
  __builtin_amdgcn_global_load_lds((const __attribute__((address_space(1))) void*)g,
                                   (__attribute__((address_space(3))) void*)l, 16, 0, 0);
}

__device__ __forceinline__ void act(float g, float v, float d, f16& xh, f16& ah) {
  float sg = 1.f / (1.f + __expf(-g));
  float tv = 1.f - 2.f / (__expf(2.f * v) + 1.f);
  float sd = 1.f / (1.f + __expf(-d));
  xh = (f16)(sg * tv);
  ah = (f16)(0.001f + 0.998f * sd);
}

// grid = 1024 blocks (XCD-swizzled to 16 N x 64 M), 512 threads = 8 waves.
__global__ __launch_bounds__(512, 2) void gemm_fused_kernel(
    const f16* __restrict__ A, const f16* __restrict__ Bt,
    const float* __restrict__ bg, const float* __restrict__ bv,
    const float* __restrict__ bd,
    f16* __restrict__ xsA, f16* __restrict__ aA,
    float* __restrict__ P, float* __restrict__ H,
    float* __restrict__ SP, float* __restrict__ SH) {
  __shared__ __attribute__((aligned(16))) f16 smem[SMEM_H];
  const int tid = threadIdx.x;
  const int lane = tid & 63;
  const int wave = tid >> 6;

  // bijective XCD swizzle (nwg=1024 % 8 == 0): XCD c owns 128 consecutive
  // orig ids = 8 M-panels x 16 N-blocks, N-major -> A panel stays L2-hot.
  const int wg = blockIdx.x;
  const int orig = (wg & 7) * 128 + (wg >> 3);
  const int bx = orig & 15;   // N block 0..15
  const int by = orig >> 4;   // M block 0..63
  const int m0 = by * BM;
  const int bn0 = bx * BN;    // interleaved B row base (multiple of 3)

  // bias loads issued before the K-loop; ledger closes for ANY compiler
  // placement (first / interleaved / sunk to epilogue) — counted waits only
  // need an upper bound on older outstanding entries.
  const int d = tid & 63;        // channel within block (64 channels)
  const int gd = (bx << 6) + d;  // global channel
  const float Bg = bg[gd], Bv = bv[gd], Bd_ = bd[gd];

  // ---- staging: wave-role-split. waves 0-3 stage A (4 chunks of 64 rows),
  // waves 4-7 stage B (3 chunks). Per 256-thread group: 64 rows x 4 slots of
  // 8 halves. LDS dest linear (gl_lds rule); global SOURCE slot pre-swizzled:
  // LDS[row][p] = global[row][p ^ ((row>>1)&3)] (involution, rule #21).
  const int tau = tid & 255;
  const int srow = tau >> 2;                         // 0..63
  const int sslot = (tau & 3) ^ ((tau >> 3) & 3);    // = p ^ ((srow>>1)&3)
  const f16* aSrc = A + (size_t)(m0 + srow) * K_TOT + sslot * 8;
  const f16* bSrc = Bt + (size_t)(bn0 + srow) * K_TOT + sslot * 8;
  f16* aDst0 = smem + AS_OFF + tau * 8;              // + buf*ABUF + r*2048
  f16* bDst0 = smem + BS_OFF + tau * 8;              // + buf*BBUF + r*2048

  // ---- fragment addressing ----
  const int wm = (wave >> 1) * 64;  // 0/64/128/192
  const int wn = (wave & 1) * 96;   // 0/96
  const int lm = lane & 15;
  // read-side swizzle: logical slot q=lane>>4 sits at q ^ ((row>>1)&3);
  // (row>>1)&3 == (lm>>1)&3 (wm, i*16, j*16 are all 0 mod 8).
  const int kswz = (((lane >> 4) ^ ((lm >> 1) & 3)) << 3);

  f32x4 acc[4][6] = {};

  // stage(tile, buf): A-waves 4 gl_lds16, B-waves 3.
  auto STAGE = [&](int tile, int buf) {
    const size_t k0 = (size_t)tile * BK;
    if (wave < 4) {
#pragma unroll
      for (int r = 0; r < 4; ++r)
        gl_lds16(aSrc + (size_t)r * 64 * K_TOT + k0, aDst0 + buf * ABUF + r * 2048);
    } else {
#pragma unroll
      for (int r = 0; r < 3; ++r)
        gl_lds16(bSrc + (size_t)r * 64 * K_TOT + k0, bDst0 + buf * BBUF + r * 2048);
    }
  };

  // ---- prologue: 3 tiles in flight (A-waves 12 loads, B-waves 9) ----
  STAGE(0, 0);
  STAGE(1, 1);
  STAGE(2, 2);

  // ---- main loop: 32 K-tiles, triple buffer, 2-iteration issue slack.
  // iter t: [role vmcnt: tile t landed, t+1/t+2 still flying] [barrier]
  // [10 ds_read + 24 MFMA (setprio-wrapped) on buf t%3] [barrier]
  // [stage t+3 into buf t%3].
  int bufc = 0;
  for (int t = 0; t < 32; ++t) {
    if (t < 30) {
      if (wave < 4) asm volatile("s_waitcnt vmcnt(8)" ::: "memory");
      else          asm volatile("s_waitcnt vmcnt(6)" ::: "memory");
    } else if (t == 30) {
      if (wave < 4) asm volatile("s_waitcnt vmcnt(4)" ::: "memory");
      else          asm volatile("s_waitcnt vmcnt(3)" ::: "memory");
    } else {
      asm volatile("s_waitcnt vmcnt(0)" ::: "memory");
    }
    __builtin_amdgcn_s_barrier();

    const f16* Acur = smem + AS_OFF + bufc * ABUF;
    const f16* Bcur = smem + BS_OFF + bufc * BBUF;
    f16x8 af[4], bf[6];
#pragma unroll
    for (int i = 0; i < 4; ++i)
      af[i] = *(const f16x8*)&Acur[(wm + i * 16 + lm) * BK + kswz];
#pragma unroll
    for (int j = 0; j < 6; ++j)
      bf[j] = *(const f16x8*)&Bcur[(wn + j * 16 + lm) * BK + kswz];
    __builtin_amdgcn_s_setprio(1);
#pragma unroll
    for (int i = 0; i < 4; ++i)
#pragma unroll
      for (int j = 0; j < 6; ++j)
        acc[i][j] = __builtin_amdgcn_mfma_f32_16x16x32_f16(af[i], bf[j], acc[i][j], 0, 0, 0);
    __builtin_amdgcn_s_setprio(0);

    if (t < 29) {
      __builtin_amdgcn_s_barrier();  // all waves consumed buf t%3
      STAGE(t + 3, bufc);
    }
    bufc = (bufc == 2) ? 0 : bufc + 1;
  }
  __syncthreads();  // full drain before epilogue overlays the staging LDS

  // ---- epilogue: four 64-row quarter-passes through LDS overlay ----
  f16* Raw = smem;
  f16* xsL = smem + 12800;
  f16* aLs = smem + 17408;
  float* segP = (float*)(smem + 22016);  // [16][64] chunk p per (chunk, channel)
  float* segH = segP + 1024;             // [16][64] chunk h
  const int cc = (tid >> 6) & 3;         // chunk within quarter (tid<256 active)

#pragma unroll
  for (int qq = 0; qq < 4; ++qq) {
    // 1) wave-pair qq dumps its acc rows (64 rows x 192 cols) into Raw
    if ((wave >> 1) == qq) {
      const int r0 = (lane >> 4) << 2;   // local row in quarter
      const int c0 = wn + lm;            // channel-triple column
#pragma unroll
      for (int i = 0; i < 4; ++i)
#pragma unroll
        for (int j = 0; j < 6; ++j)
#pragma unroll
          for (int r = 0; r < 4; ++r)
            Raw[(r0 + i * 16 + r) * RAWP + c0 + j * 16] = (f16)acc[i][j][r];
    }
    __syncthreads();

    // 2) activation + chunk-local scan; thread = (chunk cc, channel d)
    if (tid < 256) {
      float p = 1.f, h = 0.f;
#pragma unroll
      for (int i = 0; i < CLEN; ++i) {
        const int r = cc * CLEN + i;
        const f16* t3 = &Raw[r * RAWP + 3 * d];
        f16 xh, ah;
        act((float)t3[0] + Bg, (float)t3[1] + Bv, (float)t3[2] + Bd_, xh, ah);
        xsL[r * XSP + d] = xh;
        aLs[r * XSP + d] = ah;
        // use ROUNDED values so scan3 recomposition is exactly consistent
        float xf = (float)xh, af_ = (float)ah;
        h = af_ * h + xf;
        p *= af_;
      }
      const int gs = (m0 >> 4) + qq * 4 + cc;  // global chunk index = m/16
      P[(size_t)gs * D_DIM + gd] = p;
      H[(size_t)gs * D_DIM + gd] = h;
      segP[(qq * 4 + cc) * 64 + d] = p;
      segH[(qq * 4 + cc) * 64 + d] = h;
    }
    __syncthreads();

    // 3) coalesced xs/a global stores (64 rows x 64 cols)
    {
      const int row = tid >> 3;
      const int col = (tid & 7) * 8;
      const size_t gi = (size_t)(m0 + qq * 64 + row) * D_DIM + (bx << 6) + col;
      *(f16x8*)(xsA + gi) = *(const f16x8*)&xsL[row * XSP + col];
      *(f16x8*)(aA + gi) = *(const f16x8*)&aLs[row * XSP + col];
    }
    __syncthreads();  // next quarter overwrites Raw/xsL/aLs
  }

  // ---- segment aggregate: block's 256 rows = segment `by` (same fold order
  // as the original scan2a -> bitwise-identical SP/SH).
  if (tid < 64) {
    float ps = 1.f, hs = 0.f;
#pragma unroll
    for (int s = 0; s < 16; ++s) {
      const float pp = segP[s * 64 + tid];
      const float hh = segH[s * 64 + tid];
      hs = pp * hs + hh;
      ps *= pp;
    }
    const size_t so = (size_t)by * D_DIM + (bx << 6) + tid;
    SP[so] = ps;
    SH[so] = hs;
  }
}

// ---------------- scan pass 3: rebuild carry from SP/SH + P/H, rescan, out ----------------
// ck (thus segment s, chain lengths) is block-uniform -> non-divergent chains.
// Arithmetic order matches the original scan2bc -> identical carry values.
__global__ void scan3_kernel(const f16* __restrict__ xsA, const f16* __restrict__ aA,
                             const float* __restrict__ P, const float* __restrict__ Hc,
                             const float* __restrict__ SP, const float* __restrict__ SH,
                             float* __restrict__ out) {
  const int u = blockIdx.x * 256 + threadIdx.x;
  const int cg = u & 127;
  const int b = (u >> 7) & 3;
  const int ck = u >> 9;   // 0..255, uniform per block
  const int s = ck >> 4;   // segment index, uniform per block
  const int ch = cg * 8;

  float h[8];
#pragma unroll
  for (int j = 0; j < 8; ++j) h[j] = 0.f;

  // carry chain over preceding segment aggregates (<=15 steps, L2-resident)
  for (int s2 = 0; s2 < s; ++s2) {
    const size_t off = (size_t)(b * NSEG + s2) * D_DIM + ch;
    f32x4 sp0 = *(const f32x4*)(SP + off);
    f32x4 sp1 = *(const f32x4*)(SP + off + 4);
    f32x4 sh0 = *(const f32x4*)(SH + off);
    f32x4 sh1 = *(const f32x4*)(SH + off + 4);
#pragma unroll
    for (int j = 0; j < 4; ++j) h[j] = sp0[j] * h[j] + sh0[j];
#pragma unroll
    for (int j = 0; j < 4; ++j) h[4 + j] = sp1[j] * h[4 + j] + sh1[j];
  }
  // carry chain over preceding chunks within this segment (<=15 steps)
  for (int c = s * SEG; c < ck; ++c) {
    const size_t off = (size_t)(b * CPB + c) * D_DIM + ch;
    f32x4 p0 = *(const f32x4*)(P + off);
    f32x4 p1 = *(const f32x4*)(P + off + 4);
    f32x4 h0 = *(const f32x4*)(Hc + off);
    f32x4 h1 = *(const f32x4*)(Hc + off + 4);
#pragma unroll
    for (int j = 0; j < 4; ++j) h[j] = p0[j] * h[j] + h0[j];
#pragma unroll
    for (int j = 0; j < 4; ++j) h[4 + j] = p1[j] * h[4 + j] + h1[j];
  }

  // rescan the 16 timesteps of this chunk, write f32 output
  const int t0 = ck * CLEN;
#pragma unroll 4
  for (int t = t0; t < t0 + CLEN; ++t) {
    const size_t m = (size_t)b * S_LEN + t;
    f16x8 xs8 = *(const f16x8*)(xsA + m * D_DIM + ch);
    f16x8 a8 = *(const f16x8*)(aA + m * D_DIM + ch);
#pragma unroll
    for (int j = 0; j < 8; ++j) h[j] = (float)a8[j] * h[j] + (float)xs8[j];
    float* op = out + m * D_DIM + ch;
    *(f32x4*)op = *(f32x4*)h;
    *(f32x4*)(op + 4) = *(f32x4*)(h + 4);
  }
}

extern "C" void kernel_launch(void* const* d_in, const int* in_sizes, int n_in,
                              void* d_out, int out_size, void* d_ws, size_t ws_size,
                              hipStream_t stream) {
  const float* x = (const float*)d_in[0];
  const float* Wg = (const float*)d_in[1];
  const float* bg = (const float*)d_in[2];
  const float* Wv = (const float*)d_in[3];
  const float* bv = (const float*)d_in[4];
  const float* Wd = (const float*)d_in[5];
  const float* bd = (const float*)d_in[6];
  float* out = (float*)d_out;

  // workspace layout (~110.5 MiB). No carry buffer (scan3 rebuilds carries).
  char* ws = (char*)d_ws;
  f16* Ah = (f16*)(ws);                     // 33,554,432 B
  f16* Bh = (f16*)(ws + 33554432);          // 6,291,456 B (interleaved weights)
  f16* xsA = (f16*)(ws + 39845888);         // 33,554,432 B
  f16* aA = (f16*)(ws + 73400320);          // 33,554,432 B
  float* P = (float*)(ws + 106954752);      // NCHUNK*1024*4 = 4,194,304 B
  float* H = (float*)(ws + 111149056);      // 4,194,304 B
  float* SP = (float*)(ws + 115343360);     // 262,144 B
  float* SH = (float*)(ws + 115605504);     // 262,144 B  (end 115,867,648)

  cvt_all_kernel<<<9728, 256, 0, stream>>>(x, Wg, Wv, Wd, Ah, Bh);
  gemm_fused_kernel<<<1024, 512, 0, stream>>>(Ah, Bh, bg, bv, bd, xsA, aA, P, H, SP, SH);
  scan3_kernel<<<512, 256, 0, stream>>>(xsA, aA, P, H, SP, SH, out);
}